// Round 9
// baseline (163.422 us; speedup 1.0000x reference)
//
#include <hip/hip_runtime.h>

#define D 64
#define TILE 128
#define W 8             // B-tiles per block (chunk length)

typedef __attribute__((ext_vector_type(8))) short short8;
typedef __attribute__((ext_vector_type(4))) float f32x4;
typedef __attribute__((ext_vector_type(8))) unsigned short ushort8;

#define CC     (-0.7213475204444817f)   // -log2(e)/(2*sigma^2), sigma=1
#define SCALE  (1.2011224087864498f)    // sqrt(2*log2(e)); dot(scaled) = -2C*dot
#define THR    (-28.0f)                 // drop terms < 2^-28: total mass < 3 -> <3e-8 on output

typedef const __attribute__((address_space(1))) void* gptr_t;
typedef __attribute__((address_space(3))) void* lptr_t;

// ---------------------------------------------------------------------------
// Prep: fp32 -> bf16 (RNE), PRE-SCALED by sqrt(2*log2 e), pre-swizzled within
// each 128B row (chunk' = chunk ^ (row&7), chunk = 8 bf16 = 16B) so linear
// global_load_lds staging + swizzled ds_read_b128 is bank-conflict-free.
// Norms stored PRE-MULTIPLIED by C. Padded rows: zeros + C*1e30.
// ---------------------------------------------------------------------------
__global__ void prep_kernel(const float* __restrict__ X, const float* __restrict__ Y,
                            unsigned short* __restrict__ Xbf, unsigned short* __restrict__ Ybf,
                            float* __restrict__ nx, float* __restrict__ ny,
                            int nX, int nY, int padN) {
    int t = blockIdx.x * blockDim.x + threadIdx.x;
    int half = padN * 8;
    if (t >= 2 * half) return;

    const float* src; unsigned short* dst; float* nrm; int n; int tt;
    if (t < half) { src = X; dst = Xbf; nrm = nx; n = nX; tt = t; }
    else          { src = Y; dst = Ybf; nrm = ny; n = nY; tt = t - half; }

    int row = tt >> 3, c8 = tt & 7;

    float v[8];
    float ss = 0.f;
    if (row < n) {
        const float4* p = (const float4*)(src + (size_t)row * D + c8 * 8);
        float4 f0 = p[0], f1 = p[1];
        v[0] = f0.x; v[1] = f0.y; v[2] = f0.z; v[3] = f0.w;
        v[4] = f1.x; v[5] = f1.y; v[6] = f1.z; v[7] = f1.w;
#pragma unroll
        for (int i = 0; i < 8; ++i) ss += v[i] * v[i];
    } else {
#pragma unroll
        for (int i = 0; i < 8; ++i) v[i] = 0.f;
    }

    ss += __shfl_xor(ss, 1, 64);
    ss += __shfl_xor(ss, 2, 64);
    ss += __shfl_xor(ss, 4, 64);

    ushort8 o;
#pragma unroll
    for (int i = 0; i < 8; ++i) {
        unsigned u = __float_as_uint(v[i] * SCALE);
        o[i] = (unsigned short)((u + 0x7fffu + ((u >> 16) & 1u)) >> 16);   // RNE
    }
    *(ushort8*)(dst + (size_t)row * D + ((c8 ^ (row & 7)) << 3)) = o;

    if (c8 == 0) nrm[row] = (row < n) ? (CC * ss) : (CC * 1e30f);
}

// ---------------------------------------------------------------------------
// Per-tile max of C*norm (for the fast-path bound): vmax[which][tile].
// Padded rows carry C*1e30 (very negative) -> never the max.
// ---------------------------------------------------------------------------
__global__ void tilemax_kernel(const float* __restrict__ nx, const float* __restrict__ ny,
                               float* __restrict__ vmx, int NT) {
    const int tile = blockIdx.x, which = blockIdx.y;
    const float* src = which ? ny : nx;
    float v = src[(size_t)tile * TILE + threadIdx.x];
#pragma unroll
    for (int m = 32; m > 0; m >>= 1) v = fmaxf(v, __shfl_xor(v, m, 64));
    __shared__ float sh[2];
    if ((threadIdx.x & 63) == 0) sh[threadIdx.x >> 6] = v;
    __syncthreads();
    if (threadIdx.x == 0) vmx[which * NT + tile] = fmaxf(sh[0], sh[1]);
}

// ---------------------------------------------------------------------------
// Persistent-A gram kernel, ONE barrier per tile. A-frags + A-norms (u4 =
// MFMA C-in) in registers for the whole block; B-tile double-buffered in LDS.
// Per tile: ds_read frags(cur) -> STAGE(t+1 -> cur^1) -> 32 MFMAs -> 64-value
// max3 bound vs (mx + vmaxTile) -> [rare] exp path with norms loaded from
// global -> vmcnt(0)+lgkmcnt(0)+s_barrier. The vmcnt drain sits after ~350cyc
// of compute so stage latency is hidden; one barrier both publishes t+1 and
// retires reads of t. Fast-path VALU ~= 32 max3 + addressing only.
// z=0: xx (bj>=bi, x2 off-diag), z=1: yy, z=2: xy (full rows).
// ---------------------------------------------------------------------------
__launch_bounds__(256, 3)
__global__ void gram_kernel(const unsigned short* __restrict__ Xbf,
                            const unsigned short* __restrict__ Ybf,
                            const float* __restrict__ nx, const float* __restrict__ ny,
                            const float* __restrict__ vmx,
                            int nX, int nY, int NT, int CH, float* __restrict__ part) {
    __shared__ unsigned short Bbuf[2][TILE * D];   // 2 x 16KB
    __shared__ float red[4];

    const int c   = blockIdx.x;
    const int bi  = blockIdx.y;
    const int z   = blockIdx.z;
    const int tid = threadIdx.x;
    const int lin = (z * NT + bi) * CH + c;

    const int bj0 = (z < 2 ? bi : 0) + c * W;
    int ntiles = NT - bj0; if (ntiles > W) ntiles = W;
    if (ntiles <= 0) { if (tid == 0) part[lin] = 0.f; return; }

    const unsigned short* Abase; const unsigned short* Bbase;
    const float* nA; const float* nB; const float* vmB; int rA;
    if (z == 0)      { Abase = Xbf; Bbase = Xbf; nA = nx; nB = nx; vmB = vmx;      rA = nX; }
    else if (z == 1) { Abase = Ybf; Bbase = Ybf; nA = ny; nB = ny; vmB = vmx + NT; rA = nY; }
    else             { Abase = Xbf; Bbase = Ybf; nA = nx; nB = ny; vmB = vmx + NT; rA = nX; }
    vmB += bj0;

    const int a0 = bi * TILE;
    const int w = tid >> 6, lane = tid & 63;
    const int wm = (w & 1) * 64, wn = (w >> 1) * 64;
    const int lhi = lane >> 4, llo = lane & 15;
    const int sw = llo & 7;

    // ---- cooperative stage of one 16KB B-tile (4 gload_lds per wave) ----
    const char* Bsrc = (const char*)(Bbase + (size_t)bj0 * TILE * D);   // +16KB/tile
    auto STAGE = [&](int t, int par) {
        const char* src = Bsrc + (size_t)t * TILE * D * 2;
#pragma unroll
        for (int cIdx = 0; cIdx < 4; ++cIdx) {
            int off = w * 4096 + cIdx * 1024;
            __builtin_amdgcn_global_load_lds((gptr_t)(src + off + lane * 16),
                                             (lptr_t)((char*)&Bbuf[par][0] + off), 16, 0, 0);
        }
    };

    // ---- prologue: stage tile 0; A-frags + A-norms into registers ----
    STAGE(0, 0);

    const unsigned short* Ab = Abase + (size_t)(a0 + wm) * D;
    short8 af0[4], af1[4];
#pragma unroll
    for (int fm = 0; fm < 4; ++fm) {
        int r = fm * 16 + llo;
        af0[fm] = *(const short8*)&Ab[r * D + ((lhi       ^ sw) << 3)];
        af1[fm] = *(const short8*)&Ab[r * D + (((4 + lhi) ^ sw) << 3)];
    }
    f32x4 u4[4];                                           // exact C-in layout
    const float* uptr = nA + a0 + wm + lhi * 4;
#pragma unroll
    for (int fm = 0; fm < 4; ++fm) u4[fm] = *(const f32x4*)(uptr + fm * 16);

    const int bb0 = (lhi       ^ sw) << 3;    // element offset in row, ks=0
    const int bb1 = ((4 + lhi) ^ sw) << 3;    // ks=1

    float local = 0.f;

    asm volatile("s_waitcnt vmcnt(0)" ::: "memory");
    __builtin_amdgcn_s_barrier();              // tile 0 staged

    // ---- main loop: ONE barrier per tile ----
    for (int t = 0; t < ntiles; ++t) {
        const int cur = t & 1;
        const float vmT = vmB[t];              // uniform scalar (per-tile max C*n_j)

        // B fragments from LDS (swizzled rows -> conflict-free)
        short8 bf0[4], bf1[4];
#pragma unroll
        for (int fn = 0; fn < 4; ++fn) {
            int r = (wn + fn * 16 + llo) * D;
            bf0[fn] = *(const short8*)&Bbuf[cur][r + bb0];
            bf1[fn] = *(const short8*)&Bbuf[cur][r + bb1];
        }

        if (t + 1 < ntiles) STAGE(t + 1, cur ^ 1);   // into the OTHER buffer

        // acc = u4 (C-in) + dot-part; after both k-steps: acc = C*n_i - 2C*dot
        f32x4 acc[4][4];
        __builtin_amdgcn_s_setprio(1);
#pragma unroll
        for (int fm = 0; fm < 4; ++fm)
#pragma unroll
            for (int fn = 0; fn < 4; ++fn) {
                acc[fm][fn] = __builtin_amdgcn_mfma_f32_16x16x32_bf16(af0[fm], bf0[fn], u4[fm], 0, 0, 0);
                acc[fm][fn] = __builtin_amdgcn_mfma_f32_16x16x32_bf16(af1[fm], bf1[fn], acc[fm][fn], 0, 0, 0);
            }
        __builtin_amdgcn_s_setprio(0);

        // ---- 64-value bound, max3-shaped (groups of 3) ----
        float q[16];
#pragma unroll
        for (int fm = 0; fm < 4; ++fm)
#pragma unroll
            for (int fn = 0; fn < 4; ++fn) {
                f32x4 a = acc[fm][fn];
                q[fm * 4 + fn] = fmaxf(fmaxf(a[0], a[1]), fmaxf(a[2], a[3]));
            }
        float t0 = fmaxf(fmaxf(q[0],  q[1]),  q[2]);
        float t1 = fmaxf(fmaxf(q[3],  q[4]),  q[5]);
        float t2 = fmaxf(fmaxf(q[6],  q[7]),  q[8]);
        float t3 = fmaxf(fmaxf(q[9],  q[10]), q[11]);
        float t4 = fmaxf(fmaxf(q[12], q[13]), q[14]);
        float mx = fmaxf(fmaxf(fmaxf(t0, t1), t2), fmaxf(fmaxf(t3, t4), q[15]));

        const bool diag = (z < 2) && (c == 0) && (t == 0);   // bj==bi tile
        if (diag) {
            const float* nrow = nB + (size_t)(bj0 + t) * TILE + wn + llo;
            float vc[4];
#pragma unroll
            for (int fn = 0; fn < 4; ++fn) vc[fn] = nrow[fn * 16];
            float ts = 0.f;
#pragma unroll
            for (int fm = 0; fm < 4; ++fm)
#pragma unroll
                for (int fn = 0; fn < 4; ++fn)
#pragma unroll
                    for (int rr = 0; rr < 4; ++rr) {
                        float term = __builtin_amdgcn_exp2f(fminf(acc[fm][fn][rr] + vc[fn], 0.f));
                        int gm = wm + fm * 16 + lhi * 4 + rr;
                        int gn = wn + fn * 16 + llo;
                        if (gm == gn && a0 + gm < rA) term = 1.0f;
                        ts += term;
                    }
            local += ts;                       // diagonal tile, weight 1
        } else if (__any(mx + vmT > THR)) {
            // rare path (~0.04% of tiles): norms straight from global (L2-hot)
            const float* nrow = nB + (size_t)(bj0 + t) * TILE + wn + llo;
            float vc[4];
#pragma unroll
            for (int fn = 0; fn < 4; ++fn) vc[fn] = nrow[fn * 16];
            float ts = 0.f;
#pragma unroll
            for (int fm = 0; fm < 4; ++fm)
#pragma unroll
                for (int fn = 0; fn < 4; ++fn)
#pragma unroll
                    for (int rr = 0; rr < 4; ++rr)
                        ts += __builtin_amdgcn_exp2f(fminf(acc[fm][fn][rr] + vc[fn], 0.f));
            if (z < 2) ts *= 2.f;              // symmetric off-diagonal
            local += ts;
        }

        // one barrier: publishes stage(t+1) AND retires everyone's reads of t
        asm volatile("s_waitcnt vmcnt(0) lgkmcnt(0)" ::: "memory");
        __builtin_amdgcn_s_barrier();
    }

    // ---- block reduction -> per-block partial ----
#pragma unroll
    for (int mm = 32; mm > 0; mm >>= 1) local += __shfl_xor(local, mm, 64);
    if (lane == 0) red[w] = local;
    __syncthreads();
    if (tid == 0) part[lin] = red[0] + red[1] + red[2] + red[3];
}

// ---------------------------------------------------------------------------
// Final reduce over 3 x NT x CH partials (double), combine MMD.
// ---------------------------------------------------------------------------
__global__ void reduce_kernel(const float* __restrict__ part, float* __restrict__ out,
                              int seg, int nX, int nY) {
    __shared__ double sh[3][4];
    const int tid = threadIdx.x;
    double s0 = 0, s1 = 0, s2 = 0;
    for (int i = tid; i < seg; i += 256) {
        s0 += (double)part[i];
        s1 += (double)part[seg + i];
        s2 += (double)part[2 * seg + i];
    }
#pragma unroll
    for (int m = 32; m > 0; m >>= 1) {
        s0 += __shfl_xor(s0, m, 64);
        s1 += __shfl_xor(s1, m, 64);
        s2 += __shfl_xor(s2, m, 64);
    }
    const int w = tid >> 6, lane = tid & 63;
    if (lane == 0) { sh[0][w] = s0; sh[1][w] = s1; sh[2][w] = s2; }
    __syncthreads();
    if (tid == 0) {
        double xx = sh[0][0] + sh[0][1] + sh[0][2] + sh[0][3];
        double yy = sh[1][0] + sh[1][1] + sh[1][2] + sh[1][3];
        double xy = sh[2][0] + sh[2][1] + sh[2][2] + sh[2][3];
        out[0] = (float)(xx / ((double)nX * (double)nX)
                       + yy / ((double)nY * (double)nY)
                       - 2.0 * xy / ((double)nX * (double)nY));
    }
}

extern "C" void kernel_launch(void* const* d_in, const int* in_sizes, int n_in,
                              void* d_out, int out_size, void* d_ws, size_t ws_size,
                              hipStream_t stream) {
    const float* X = (const float*)d_in[0];
    const float* Y = (const float*)d_in[1];
    const int nX = in_sizes[0] / D;
    const int nY = in_sizes[1] / D;
    const int nMax = nX > nY ? nX : nY;
    const int NT   = (nMax + TILE - 1) / TILE;
    const int padN = NT * TILE;
    const int CH   = (NT + W - 1) / W;

    // ws layout (256B-aligned):
    //   part[3*NT*CH] | nx[padN] | ny[padN] | vmx[2*NT] | Xbf[padN*64] bf16 | Ybf[padN*64] bf16
    char* ws = (char*)d_ws;
    size_t off = 0;
    float* part = (float*)(ws + off); off += ((size_t)3 * NT * CH * 4 + 255) & ~(size_t)255;
    float* nxp  = (float*)(ws + off); off += ((size_t)padN * 4 + 255) & ~(size_t)255;
    float* nyp  = (float*)(ws + off); off += ((size_t)padN * 4 + 255) & ~(size_t)255;
    float* vmx  = (float*)(ws + off); off += ((size_t)2 * NT * 4 + 255) & ~(size_t)255;
    unsigned short* Xbf = (unsigned short*)(ws + off); off += ((size_t)padN * D * 2 + 255) & ~(size_t)255;
    unsigned short* Ybf = (unsigned short*)(ws + off);

    int chunks = 2 * padN * 8;
    prep_kernel<<<(chunks + 255) / 256, 256, 0, stream>>>(X, Y, Xbf, Ybf, nxp, nyp, nX, nY, padN);

    dim3 gvm(NT, 2, 1);
    tilemax_kernel<<<gvm, 128, 0, stream>>>(nxp, nyp, vmx, NT);

    dim3 grid(CH, NT, 3);
    gram_kernel<<<grid, 256, 0, stream>>>(Xbf, Ybf, nxp, nyp, vmx, nX, nY, NT, CH, part);

    reduce_kernel<<<1, 256, 0, stream>>>(part, (float*)d_out, NT * CH, nX, nY);
}